// Round 1
// baseline (121.192 us; speedup 1.0000x reference)
//
#include <hip/hip_runtime.h>
#include <math.h>

#define S_DIM 512
#define N_NODE 1024
#define H_DIM 128
#define Z_DIM 64
#define T_START 64
#define T_CNT 353          // end - start = 417 - 64
#define NEG_DIST 85        // S // 6
#define TIMESPAN 4
#define M_SAMP 8
#define EPS_F 1e-8f

// ---------------------------------------------------------------------------
// Kernel 1: mean over nodes (axis=1).  blockIdx < S_DIM -> all_h row, else all_z.
// 256 threads; float4 vector loads; LDS tree-reduce across n-groups.
// ---------------------------------------------------------------------------
__global__ __launch_bounds__(256) void pool_kernel(
        const float* __restrict__ all_h, const float* __restrict__ all_z,
        float* __restrict__ hm, float* __restrict__ zm) {
    __shared__ float4 red[256];
    const int tid = threadIdx.x;
    const int b = blockIdx.x;
    if (b < S_DIM) {
        // h: 128 floats/row = 32 float4; 8 n-groups
        const int h4 = tid & 31, grp = tid >> 5;
        const float4* p = (const float4*)(all_h + (size_t)b * N_NODE * H_DIM);
        float4 acc = make_float4(0.f, 0.f, 0.f, 0.f);
        for (int n = grp; n < N_NODE; n += 8) {
            float4 v = p[n * 32 + h4];
            acc.x += v.x; acc.y += v.y; acc.z += v.z; acc.w += v.w;
        }
        red[grp * 32 + h4] = acc;
        __syncthreads();
        for (int st = 4; st >= 1; st >>= 1) {
            if (grp < st) {
                float4 o = red[(grp + st) * 32 + h4];
                float4 m = red[grp * 32 + h4];
                m.x += o.x; m.y += o.y; m.z += o.z; m.w += o.w;
                red[grp * 32 + h4] = m;
            }
            __syncthreads();
        }
        if (grp == 0) {
            float4 r = red[h4];
            const float inv = 1.0f / (float)N_NODE;
            float4 o = make_float4(r.x * inv, r.y * inv, r.z * inv, r.w * inv);
            ((float4*)(hm + (size_t)b * H_DIM))[h4] = o;
        }
    } else {
        // z: 64 floats/row = 16 float4; 16 n-groups
        const int s = b - S_DIM;
        const int h4 = tid & 15, grp = tid >> 4;
        const float4* p = (const float4*)(all_z + (size_t)s * N_NODE * Z_DIM);
        float4 acc = make_float4(0.f, 0.f, 0.f, 0.f);
        for (int n = grp; n < N_NODE; n += 16) {
            float4 v = p[n * 16 + h4];
            acc.x += v.x; acc.y += v.y; acc.z += v.z; acc.w += v.w;
        }
        red[grp * 16 + h4] = acc;
        __syncthreads();
        for (int st = 8; st >= 1; st >>= 1) {
            if (grp < st) {
                float4 o = red[(grp + st) * 16 + h4];
                float4 m = red[grp * 16 + h4];
                m.x += o.x; m.y += o.y; m.z += o.z; m.w += o.w;
                red[grp * 16 + h4] = m;
            }
            __syncthreads();
        }
        if (grp == 0) {
            float4 r = red[h4];
            const float inv = 1.0f / (float)N_NODE;
            float4 o = make_float4(r.x * inv, r.y * inv, r.z * inv, r.w * inv);
            ((float4*)(zm + (size_t)s * Z_DIM))[h4] = o;
        }
    }
}

// ---------------------------------------------------------------------------
// Kernel 2: h_pool = hm @ Wh^T + bh ; z_pool = zm @ Wz^T + bz ; znorm[s]
// grid = S_DIM blocks, 128 threads (one output column each)
// ---------------------------------------------------------------------------
__global__ __launch_bounds__(128) void proj_kernel(
        const float* __restrict__ hm, const float* __restrict__ zm,
        const float* __restrict__ Wh, const float* __restrict__ bh,
        const float* __restrict__ Wz, const float* __restrict__ bz,
        float* __restrict__ h_pool, float* __restrict__ z_pool,
        float* __restrict__ znorm) {
    const int s = blockIdx.x, o = threadIdx.x;
    __shared__ float lh[H_DIM];
    __shared__ float lz[Z_DIM];
    __shared__ float red[H_DIM];
    lh[o] = hm[s * H_DIM + o];
    if (o < Z_DIM) lz[o] = zm[s * Z_DIM + o];
    __syncthreads();
    float hp = bh[o];
    #pragma unroll 8
    for (int k = 0; k < H_DIM; ++k) hp = fmaf(lh[k], Wh[o * H_DIM + k], hp);
    float zp = bz[o];
    #pragma unroll 8
    for (int k = 0; k < Z_DIM; ++k) zp = fmaf(lz[k], Wz[o * Z_DIM + k], zp);
    h_pool[s * H_DIM + o] = hp;
    z_pool[s * H_DIM + o] = zp;
    red[o] = zp * zp;
    __syncthreads();
    for (int st = 64; st >= 1; st >>= 1) {
        if (o < st) red[o] += red[o + st];
        __syncthreads();
    }
    if (o == 0) znorm[s] = sqrtf(red[0]);
}

// ---------------------------------------------------------------------------
// Kernel 3: distance = sum_h [ sumsq_h - sum_h^2 / S ] / S   (1 block, 128 thr)
// ---------------------------------------------------------------------------
__global__ __launch_bounds__(128) void dist_kernel(
        const float* __restrict__ z_pool, float* __restrict__ d_out) {
    const int h = threadIdx.x;
    float sum = 0.f, sumsq = 0.f;
    for (int s = 0; s < S_DIM; ++s) {
        float v = z_pool[s * H_DIM + h];
        sum += v; sumsq += v * v;
    }
    __shared__ float red[H_DIM];
    red[h] = sumsq - sum * sum / (float)S_DIM;
    __syncthreads();
    for (int st = 64; st >= 1; st >>= 1) {
        if (h < st) red[h] += red[h + st];
        __syncthreads();
    }
    if (h == 0) d_out[1] = red[0] / (float)S_DIM;
}

// ---------------------------------------------------------------------------
// Kernel 4: per-t NCE partial. grid = T_CNT, 128 threads.
//   c = h_pool[T_START+t] @ Wphi^T + bphi ; cnorm
//   32 (i,m) pairs: cosine sim with z_pool[row], row = t+T_START+(i+1)+off(m)
//   log-softmax over m, take index 0, sum over i -> partial[t]
// ---------------------------------------------------------------------------
__global__ __launch_bounds__(128) void nce_kernel(
        const float* __restrict__ h_pool, const float* __restrict__ z_pool,
        const float* __restrict__ znorm,
        const float* __restrict__ Wphi, const float* __restrict__ bphi,
        float* __restrict__ partial) {
    const int t0 = blockIdx.x;
    const int tid = threadIdx.x;
    const int row_t = T_START + t0;
    __shared__ float lh[H_DIM];
    __shared__ float c[H_DIM];
    __shared__ float red[H_DIM];
    __shared__ float sims[32];
    __shared__ float contrib[4];
    __shared__ float s_cn;

    lh[tid] = h_pool[row_t * H_DIM + tid];
    __syncthreads();
    float cv = bphi[tid];
    #pragma unroll 8
    for (int k = 0; k < H_DIM; ++k) cv = fmaf(lh[k], Wphi[tid * H_DIM + k], cv);
    c[tid] = cv;
    red[tid] = cv * cv;
    __syncthreads();
    for (int st = 64; st >= 1; st >>= 1) {
        if (tid < st) red[tid] += red[tid + st];
        __syncthreads();
    }
    if (tid == 0) s_cn = fmaxf(sqrtf(red[0]), EPS_F);
    __syncthreads();
    const float cnorm = s_cn;

    // 32 pairs, 4 lanes per pair
    const int p = tid >> 2, l4 = tid & 3;
    const int i = p >> 3, m = p & 7;
    const int off = (m == 0) ? 0 : (NEG_DIST + m - 1);
    const int row = row_t + (i + 1) + off;
    const float* zr = z_pool + row * H_DIM;
    float num = 0.f;
    #pragma unroll 8
    for (int k = l4 * 32; k < l4 * 32 + 32; ++k) num = fmaf(zr[k], c[k], num);
    num += __shfl_xor(num, 1);
    num += __shfl_xor(num, 2);
    if (l4 == 0) {
        float den = fmaxf(znorm[row], EPS_F) * cnorm;
        sims[p] = num / den;
    }
    __syncthreads();
    if (tid < 4) {
        const float* sm = sims + tid * 8;
        float mx = sm[0];
        #pragma unroll
        for (int k = 1; k < M_SAMP; ++k) mx = fmaxf(mx, sm[k]);
        float se = 0.f;
        #pragma unroll
        for (int k = 0; k < M_SAMP; ++k) se += expf(sm[k] - mx);
        contrib[tid] = sm[0] - mx - logf(se);
    }
    __syncthreads();
    if (tid == 0)
        partial[t0] = contrib[0] + contrib[1] + contrib[2] + contrib[3];
}

// ---------------------------------------------------------------------------
// Kernel 5: deterministic final sum -> nce_loss. 1 block, 512 threads.
// ---------------------------------------------------------------------------
__global__ __launch_bounds__(512) void final_kernel(
        const float* __restrict__ partial, float* __restrict__ d_out) {
    const int tid = threadIdx.x;
    __shared__ float red[512];
    red[tid] = (tid < T_CNT) ? partial[tid] : 0.f;
    __syncthreads();
    for (int st = 256; st >= 1; st >>= 1) {
        if (tid < st) red[tid] += red[tid + st];
        __syncthreads();
    }
    if (tid == 0) d_out[0] = red[0] / (-1.0f * (float)T_CNT * (float)TIMESPAN);
}

extern "C" void kernel_launch(void* const* d_in, const int* in_sizes, int n_in,
                              void* d_out, int out_size, void* d_ws, size_t ws_size,
                              hipStream_t stream) {
    const float* all_h = (const float*)d_in[0];
    const float* all_z = (const float*)d_in[1];
    const float* Wh    = (const float*)d_in[2];
    const float* bh    = (const float*)d_in[3];
    const float* Wz    = (const float*)d_in[4];
    const float* bz    = (const float*)d_in[5];
    const float* Wphi  = (const float*)d_in[6];
    const float* bphi  = (const float*)d_in[7];
    float* out = (float*)d_out;

    float* ws = (float*)d_ws;
    float* hm      = ws;                       // 512*128
    float* zm      = hm + S_DIM * H_DIM;       // 512*64
    float* h_pool  = zm + S_DIM * Z_DIM;       // 512*128
    float* z_pool  = h_pool + S_DIM * H_DIM;   // 512*128
    float* znorm   = z_pool + S_DIM * H_DIM;   // 512
    float* partial = znorm + S_DIM;            // 353

    pool_kernel<<<2 * S_DIM, 256, 0, stream>>>(all_h, all_z, hm, zm);
    proj_kernel<<<S_DIM, 128, 0, stream>>>(hm, zm, Wh, bh, Wz, bz,
                                           h_pool, z_pool, znorm);
    dist_kernel<<<1, 128, 0, stream>>>(z_pool, out);
    nce_kernel<<<T_CNT, 128, 0, stream>>>(h_pool, z_pool, znorm, Wphi, bphi, partial);
    final_kernel<<<1, 512, 0, stream>>>(partial, out);
}

// Round 2
// 73.793 us; speedup vs baseline: 1.6423x; 1.6423x over previous
//
#include <hip/hip_runtime.h>
#include <math.h>

#define S_DIM 512
#define N_NODE 1024
#define H_DIM 128
#define Z_DIM 64
#define T_START 64
#define T_CNT 353          // end - start = 417 - 64
#define NEG_DIST 85        // S // 6
#define TIMESPAN 4
#define M_SAMP 8
#define EPS_F 1e-8f
#define DIST_B 4

typedef float f4 __attribute__((ext_vector_type(4)));

// ---------------------------------------------------------------------------
// Kernel 1: fused pool + projections.
//   blocks [0, T_CNT):       h-row s=T_START+b: mean -> h_pool -> c_phi + cnorm
//   blocks [T_CNT, T_CNT+S): z-row s=b-T_CNT:   mean -> z_pool + znorm
// Heavy h-blocks (512 KB reads) get low blockIdx -> dispatched first; light
// z-blocks (256 KB) fill the tail. Streaming reads are non-temporal.
// ---------------------------------------------------------------------------
__global__ __launch_bounds__(256) void pool_proj_kernel(
        const float* __restrict__ all_h, const float* __restrict__ all_z,
        const float* __restrict__ Wh,   const float* __restrict__ bh,
        const float* __restrict__ Wz,   const float* __restrict__ bz,
        const float* __restrict__ Wphi, const float* __restrict__ bphi,
        float* __restrict__ c_phi, float* __restrict__ cnorm,
        float* __restrict__ z_pool, float* __restrict__ znorm) {
    __shared__ __align__(16) f4 red4[256];
    __shared__ __align__(16) float mrow[H_DIM];
    __shared__ __align__(16) float hrow[H_DIM];
    __shared__ float sred[H_DIM];
    const int tid = threadIdx.x;
    const int b = blockIdx.x;
    const int o = tid >> 1, half = tid & 1;

    if (b < T_CNT) {
        const int s = T_START + b;
        const int h4 = tid & 31, grp = tid >> 5;
        const f4* p = (const f4*)(all_h + (size_t)s * N_NODE * H_DIM);
        f4 acc = {0.f, 0.f, 0.f, 0.f};
        #pragma unroll 8
        for (int n = grp; n < N_NODE; n += 8)
            acc += __builtin_nontemporal_load(&p[n * 32 + h4]);
        red4[grp * 32 + h4] = acc;
        __syncthreads();
        for (int st = 4; st >= 1; st >>= 1) {
            if (grp < st) red4[grp * 32 + h4] += red4[(grp + st) * 32 + h4];
            __syncthreads();
        }
        if (grp == 0)
            *(f4*)&mrow[h4 * 4] = red4[h4] * (1.0f / (float)N_NODE);
        __syncthreads();

        // h_pool row: 2 threads per output, 64 FMA each
        {
            const float* w = Wh + o * H_DIM + half * 64;
            const float* x = mrow + half * 64;
            float ps = 0.f;
            #pragma unroll 8
            for (int k = 0; k < 64; ++k) ps = fmaf(x[k], w[k], ps);
            ps += __shfl_xor(ps, 1);
            if (half == 0) hrow[o] = ps + bh[o];
        }
        __syncthreads();
        // c_phi row + squared-norm
        {
            const float* w = Wphi + o * H_DIM + half * 64;
            const float* x = hrow + half * 64;
            float ps = 0.f;
            #pragma unroll 8
            for (int k = 0; k < 64; ++k) ps = fmaf(x[k], w[k], ps);
            ps += __shfl_xor(ps, 1);
            if (half == 0) {
                float cv = ps + bphi[o];
                c_phi[b * H_DIM + o] = cv;
                sred[o] = cv * cv;
            }
        }
        __syncthreads();
        for (int st = 64; st >= 1; st >>= 1) {
            if (tid < st) sred[tid] += sred[tid + st];
            __syncthreads();
        }
        if (tid == 0) cnorm[b] = fmaxf(sqrtf(sred[0]), EPS_F);
    } else {
        const int s = b - T_CNT;
        const int h4 = tid & 15, grp = tid >> 4;
        const f4* p = (const f4*)(all_z + (size_t)s * N_NODE * Z_DIM);
        f4 acc = {0.f, 0.f, 0.f, 0.f};
        #pragma unroll 8
        for (int n = grp; n < N_NODE; n += 16)
            acc += __builtin_nontemporal_load(&p[n * 16 + h4]);
        red4[grp * 16 + h4] = acc;
        __syncthreads();
        for (int st = 8; st >= 1; st >>= 1) {
            if (grp < st) red4[grp * 16 + h4] += red4[(grp + st) * 16 + h4];
            __syncthreads();
        }
        if (grp == 0)
            *(f4*)&mrow[h4 * 4] = red4[h4] * (1.0f / (float)N_NODE);  // mz in mrow[0:64]
        __syncthreads();

        // z_pool row: 2 threads per output, 32 FMA each
        const float* w = Wz + o * Z_DIM + half * 32;
        const float* x = mrow + half * 32;
        float ps = 0.f;
        #pragma unroll 8
        for (int k = 0; k < 32; ++k) ps = fmaf(x[k], w[k], ps);
        ps += __shfl_xor(ps, 1);
        if (half == 0) {
            float zp = ps + bz[o];
            z_pool[s * H_DIM + o] = zp;
            sred[o] = zp * zp;
        }
        __syncthreads();
        for (int st = 64; st >= 1; st >>= 1) {
            if (tid < st) sred[tid] += sred[tid + st];
            __syncthreads();
        }
        if (tid == 0) znorm[s] = sqrtf(sred[0]);
    }
}

// ---------------------------------------------------------------------------
// Kernel 2: blocks [0,T_CNT): per-t NCE partial (c_phi precomputed).
//           blocks [T_CNT, T_CNT+DIST_B): per-column partial sum/sumsq of
//           z_pool over an s-chunk of 128 rows (for the distance term).
// ---------------------------------------------------------------------------
__global__ __launch_bounds__(128) void nce_dist_kernel(
        const float* __restrict__ c_phi, const float* __restrict__ cnorm,
        const float* __restrict__ z_pool, const float* __restrict__ znorm,
        float* __restrict__ partial, float* __restrict__ dsum,
        float* __restrict__ dsq) {
    const int b = blockIdx.x, tid = threadIdx.x;
    if (b < T_CNT) {
        __shared__ float c[H_DIM];
        __shared__ float sims[32];
        __shared__ float contrib[4];
        c[tid] = c_phi[b * H_DIM + tid];
        __syncthreads();
        const float cn = cnorm[b];
        const int pr = tid >> 2, l4 = tid & 3;
        const int i = pr >> 3, m = pr & 7;
        const int off = (m == 0) ? 0 : (NEG_DIST + m - 1);
        const int row = T_START + b + (i + 1) + off;
        const float* zr = z_pool + row * H_DIM;
        float num = 0.f;
        #pragma unroll 8
        for (int k = l4 * 32; k < l4 * 32 + 32; ++k) num = fmaf(zr[k], c[k], num);
        num += __shfl_xor(num, 1);
        num += __shfl_xor(num, 2);
        if (l4 == 0) sims[pr] = num / (fmaxf(znorm[row], EPS_F) * cn);
        __syncthreads();
        if (tid < 4) {
            const float* sm = sims + tid * 8;
            float mx = sm[0];
            #pragma unroll
            for (int k = 1; k < M_SAMP; ++k) mx = fmaxf(mx, sm[k]);
            float se = 0.f;
            #pragma unroll
            for (int k = 0; k < M_SAMP; ++k) se += expf(sm[k] - mx);
            contrib[tid] = sm[0] - mx - logf(se);
        }
        __syncthreads();
        if (tid == 0)
            partial[b] = contrib[0] + contrib[1] + contrib[2] + contrib[3];
    } else {
        const int ch = b - T_CNT;
        const int s0 = ch * (S_DIM / DIST_B);
        float sum = 0.f, sq = 0.f;
        for (int s = s0; s < s0 + S_DIM / DIST_B; ++s) {
            float v = z_pool[s * H_DIM + tid];
            sum += v;
            sq = fmaf(v, v, sq);
        }
        dsum[ch * H_DIM + tid] = sum;
        dsq[ch * H_DIM + tid] = sq;
    }
}

// ---------------------------------------------------------------------------
// Kernel 3: final deterministic reductions -> both scalars.
// ---------------------------------------------------------------------------
__global__ __launch_bounds__(512) void final_kernel(
        const float* __restrict__ partial, const float* __restrict__ dsum,
        const float* __restrict__ dsq, float* __restrict__ out) {
    const int tid = threadIdx.x;
    __shared__ float red[512];
    __shared__ float dred[H_DIM];
    red[tid] = (tid < T_CNT) ? partial[tid] : 0.f;
    if (tid < H_DIM) {
        float S = 0.f, Q = 0.f;
        #pragma unroll
        for (int c = 0; c < DIST_B; ++c) {
            S += dsum[c * H_DIM + tid];
            Q += dsq[c * H_DIM + tid];
        }
        dred[tid] = Q - S * S / (float)S_DIM;
    }
    __syncthreads();
    for (int st = 256; st >= 1; st >>= 1) {
        if (tid < st) red[tid] += red[tid + st];
        __syncthreads();
    }
    for (int st = 64; st >= 1; st >>= 1) {
        if (tid < st) dred[tid] += dred[tid + st];
        __syncthreads();
    }
    if (tid == 0) {
        out[0] = red[0] / (-1.0f * (float)T_CNT * (float)TIMESPAN);
        out[1] = dred[0] / (float)S_DIM;
    }
}

extern "C" void kernel_launch(void* const* d_in, const int* in_sizes, int n_in,
                              void* d_out, int out_size, void* d_ws, size_t ws_size,
                              hipStream_t stream) {
    const float* all_h = (const float*)d_in[0];
    const float* all_z = (const float*)d_in[1];
    const float* Wh    = (const float*)d_in[2];
    const float* bh    = (const float*)d_in[3];
    const float* Wz    = (const float*)d_in[4];
    const float* bz    = (const float*)d_in[5];
    const float* Wphi  = (const float*)d_in[6];
    const float* bphi  = (const float*)d_in[7];
    float* out = (float*)d_out;

    float* ws = (float*)d_ws;
    float* c_phi   = ws;                        // 353*128
    float* cnorm   = c_phi + T_CNT * H_DIM;     // 353
    float* z_pool  = cnorm + T_CNT;             // 512*128
    float* znorm   = z_pool + S_DIM * H_DIM;    // 512
    float* partial = znorm + S_DIM;             // 353
    float* dsum    = partial + T_CNT;           // 4*128
    float* dsq     = dsum + DIST_B * H_DIM;     // 4*128

    pool_proj_kernel<<<T_CNT + S_DIM, 256, 0, stream>>>(
        all_h, all_z, Wh, bh, Wz, bz, Wphi, bphi, c_phi, cnorm, z_pool, znorm);
    nce_dist_kernel<<<T_CNT + DIST_B, 128, 0, stream>>>(
        c_phi, cnorm, z_pool, znorm, partial, dsum, dsq);
    final_kernel<<<1, 512, 0, stream>>>(partial, dsum, dsq, out);
}

// Round 3
// 63.633 us; speedup vs baseline: 1.9045x; 1.1597x over previous
//
#include <hip/hip_runtime.h>
#include <math.h>

#define S_DIM 512
#define N_NODE 1024
#define H_DIM 128
#define Z_DIM 64
#define T_START 64
#define T_CNT 353          // end - start = 417 - 64
#define NEG_DIST 85        // S // 6
#define TIMESPAN 4
#define M_SAMP 8
#define EPS_F 1e-8f
#define DIST_B 4
#define H_CHUNKS 4         // 4 chunks of 256 nodes per h-row (128 KB each)

typedef float f4 __attribute__((ext_vector_type(4)));

// ---------------------------------------------------------------------------
// Kernel 1: uniform-granularity pooling.
//   blocks [0, S_DIM):  z-row s=b (256 KB): mean -> z_pool row + znorm
//   blocks [S_DIM, S_DIM + T_CNT*4): h-chunk (128 KB): raw partial sum only.
// z first (bigger blocks start early); 128 KB h-chunks fill the tail.
// ---------------------------------------------------------------------------
__global__ __launch_bounds__(256) void pool_kernel(
        const float* __restrict__ all_h, const float* __restrict__ all_z,
        const float* __restrict__ Wz, const float* __restrict__ bz,
        float* __restrict__ z_pool, float* __restrict__ znorm,
        float* __restrict__ hpart) {
    __shared__ __align__(16) f4 red4[256];
    __shared__ __align__(16) float mrow[H_DIM];
    __shared__ float sred[H_DIM];
    const int tid = threadIdx.x;
    const int b = blockIdx.x;

    if (b < S_DIM) {
        // ---- z row: mean over 1024 nodes + projection + norm ----
        const int s = b;
        const int h4 = tid & 15, grp = tid >> 4;
        const f4* p = (const f4*)(all_z + (size_t)s * N_NODE * Z_DIM);
        f4 acc = {0.f, 0.f, 0.f, 0.f};
        #pragma unroll 8
        for (int n = grp; n < N_NODE; n += 16)
            acc += __builtin_nontemporal_load(&p[n * 16 + h4]);
        red4[grp * 16 + h4] = acc;
        __syncthreads();
        for (int st = 8; st >= 1; st >>= 1) {
            if (grp < st) red4[grp * 16 + h4] += red4[(grp + st) * 16 + h4];
            __syncthreads();
        }
        if (grp == 0)
            *(f4*)&mrow[h4 * 4] = red4[h4] * (1.0f / (float)N_NODE);
        __syncthreads();

        const int o = tid >> 1, half = tid & 1;
        const float* w = Wz + o * Z_DIM + half * 32;
        const float* x = mrow + half * 32;
        float ps = 0.f;
        #pragma unroll 8
        for (int k = 0; k < 32; ++k) ps = fmaf(x[k], w[k], ps);
        ps += __shfl_xor(ps, 1);
        if (half == 0) {
            float zp = ps + bz[o];
            z_pool[s * H_DIM + o] = zp;
            sred[o] = zp * zp;
        }
        __syncthreads();
        for (int st = 64; st >= 1; st >>= 1) {
            if (tid < st) sred[tid] += sred[tid + st];
            __syncthreads();
        }
        if (tid == 0) znorm[s] = sqrtf(sred[0]);
    } else {
        // ---- h chunk: raw partial sum over 256 nodes ----
        const int b2 = b - S_DIM;
        const int t = b2 >> 2, ch = b2 & 3;
        const int s = T_START + t;
        const int h4 = tid & 31, grp = tid >> 5;
        const int n0 = ch * (N_NODE / H_CHUNKS);
        const f4* p = (const f4*)(all_h + (size_t)s * N_NODE * H_DIM);
        f4 acc = {0.f, 0.f, 0.f, 0.f};
        #pragma unroll 8
        for (int n = n0 + grp; n < n0 + N_NODE / H_CHUNKS; n += 8)
            acc += __builtin_nontemporal_load(&p[n * 32 + h4]);
        red4[grp * 32 + h4] = acc;
        __syncthreads();
        for (int st = 4; st >= 1; st >>= 1) {
            if (grp < st) red4[grp * 32 + h4] += red4[(grp + st) * 32 + h4];
            __syncthreads();
        }
        if (grp == 0)
            *(f4*)&hpart[b2 * H_DIM + h4 * 4] = red4[h4];
    }
}

// ---------------------------------------------------------------------------
// Kernel 2: blocks [0,T_CNT): combine own h-partials -> mean -> Wh -> Wphi
//           (all in LDS) -> cnorm -> cosine sims -> log-softmax partial.
//           blocks [T_CNT, T_CNT+DIST_B): per-column sum/sumsq of z_pool chunk.
// ---------------------------------------------------------------------------
__global__ __launch_bounds__(128) void nce_dist_kernel(
        const float* __restrict__ hpart,
        const float* __restrict__ Wh,   const float* __restrict__ bh,
        const float* __restrict__ Wphi, const float* __restrict__ bphi,
        const float* __restrict__ z_pool, const float* __restrict__ znorm,
        float* __restrict__ partial, float* __restrict__ dsum,
        float* __restrict__ dsq) {
    const int b = blockIdx.x, tid = threadIdx.x;
    if (b < T_CNT) {
        __shared__ __align__(16) float mrow[H_DIM];
        __shared__ __align__(16) float hrow[H_DIM];
        __shared__ __align__(16) float c[H_DIM];
        __shared__ float sred[H_DIM];
        __shared__ float sims[32];
        __shared__ float contrib[4];
        __shared__ float s_cn;

        const float* hp = hpart + b * (H_CHUNKS * H_DIM);
        mrow[tid] = (hp[tid] + hp[H_DIM + tid] + hp[2 * H_DIM + tid] +
                     hp[3 * H_DIM + tid]) * (1.0f / (float)N_NODE);
        __syncthreads();

        const int o = tid >> 1, half = tid & 1;
        // hrow = mrow @ Wh^T + bh   (2 threads per output, f4 loads)
        {
            const f4* w4 = (const f4*)(Wh + o * H_DIM + half * 64);
            const f4* x4 = (const f4*)(mrow + half * 64);
            float ps = 0.f;
            #pragma unroll
            for (int k = 0; k < 16; ++k) {
                f4 a = w4[k], x = x4[k];
                ps = fmaf(a.x, x.x, ps); ps = fmaf(a.y, x.y, ps);
                ps = fmaf(a.z, x.z, ps); ps = fmaf(a.w, x.w, ps);
            }
            ps += __shfl_xor(ps, 1);
            if (half == 0) hrow[o] = ps + bh[o];
        }
        __syncthreads();
        // c = hrow @ Wphi^T + bphi ; squared norm
        {
            const f4* w4 = (const f4*)(Wphi + o * H_DIM + half * 64);
            const f4* x4 = (const f4*)(hrow + half * 64);
            float ps = 0.f;
            #pragma unroll
            for (int k = 0; k < 16; ++k) {
                f4 a = w4[k], x = x4[k];
                ps = fmaf(a.x, x.x, ps); ps = fmaf(a.y, x.y, ps);
                ps = fmaf(a.z, x.z, ps); ps = fmaf(a.w, x.w, ps);
            }
            ps += __shfl_xor(ps, 1);
            if (half == 0) {
                float cv = ps + bphi[o];
                c[o] = cv;
                sred[o] = cv * cv;
            }
        }
        __syncthreads();
        for (int st = 64; st >= 1; st >>= 1) {
            if (tid < st) sred[tid] += sred[tid + st];
            __syncthreads();
        }
        if (tid == 0) s_cn = fmaxf(sqrtf(sred[0]), EPS_F);
        __syncthreads();
        const float cn = s_cn;

        // 32 (i,m) pairs, 4 lanes per cosine dot
        const int pr = tid >> 2, l4 = tid & 3;
        const int i = pr >> 3, m = pr & 7;
        const int off = (m == 0) ? 0 : (NEG_DIST + m - 1);
        const int row = T_START + b + (i + 1) + off;
        const float* zr = z_pool + row * H_DIM;
        float num = 0.f;
        #pragma unroll 8
        for (int k = l4 * 32; k < l4 * 32 + 32; ++k) num = fmaf(zr[k], c[k], num);
        num += __shfl_xor(num, 1);
        num += __shfl_xor(num, 2);
        if (l4 == 0) sims[pr] = num / (fmaxf(znorm[row], EPS_F) * cn);
        __syncthreads();
        if (tid < 4) {
            const float* sm = sims + tid * 8;
            float mx = sm[0];
            #pragma unroll
            for (int k = 1; k < M_SAMP; ++k) mx = fmaxf(mx, sm[k]);
            float se = 0.f;
            #pragma unroll
            for (int k = 0; k < M_SAMP; ++k) se += expf(sm[k] - mx);
            contrib[tid] = sm[0] - mx - logf(se);
        }
        __syncthreads();
        if (tid == 0)
            partial[b] = contrib[0] + contrib[1] + contrib[2] + contrib[3];
    } else {
        const int ch = b - T_CNT;
        const int s0 = ch * (S_DIM / DIST_B);
        float sum = 0.f, sq = 0.f;
        for (int s = s0; s < s0 + S_DIM / DIST_B; ++s) {
            float v = z_pool[s * H_DIM + tid];
            sum += v;
            sq = fmaf(v, v, sq);
        }
        dsum[ch * H_DIM + tid] = sum;
        dsq[ch * H_DIM + tid] = sq;
    }
}

// ---------------------------------------------------------------------------
// Kernel 3: final deterministic reductions -> both scalars.
// ---------------------------------------------------------------------------
__global__ __launch_bounds__(512) void final_kernel(
        const float* __restrict__ partial, const float* __restrict__ dsum,
        const float* __restrict__ dsq, float* __restrict__ out) {
    const int tid = threadIdx.x;
    __shared__ float red[512];
    __shared__ float dred[H_DIM];
    red[tid] = (tid < T_CNT) ? partial[tid] : 0.f;
    if (tid < H_DIM) {
        float S = 0.f, Q = 0.f;
        #pragma unroll
        for (int c = 0; c < DIST_B; ++c) {
            S += dsum[c * H_DIM + tid];
            Q += dsq[c * H_DIM + tid];
        }
        dred[tid] = Q - S * S / (float)S_DIM;
    }
    __syncthreads();
    for (int st = 256; st >= 1; st >>= 1) {
        if (tid < st) red[tid] += red[tid + st];
        __syncthreads();
    }
    for (int st = 64; st >= 1; st >>= 1) {
        if (tid < st) dred[tid] += dred[tid + st];
        __syncthreads();
    }
    if (tid == 0) {
        out[0] = red[0] / (-1.0f * (float)T_CNT * (float)TIMESPAN);
        out[1] = dred[0] / (float)S_DIM;
    }
}

extern "C" void kernel_launch(void* const* d_in, const int* in_sizes, int n_in,
                              void* d_out, int out_size, void* d_ws, size_t ws_size,
                              hipStream_t stream) {
    const float* all_h = (const float*)d_in[0];
    const float* all_z = (const float*)d_in[1];
    const float* Wh    = (const float*)d_in[2];
    const float* bh    = (const float*)d_in[3];
    const float* Wz    = (const float*)d_in[4];
    const float* bz    = (const float*)d_in[5];
    const float* Wphi  = (const float*)d_in[6];
    const float* bphi  = (const float*)d_in[7];
    float* out = (float*)d_out;

    float* ws = (float*)d_ws;
    float* z_pool  = ws;                              // 512*128
    float* znorm   = z_pool + S_DIM * H_DIM;          // 512
    float* hpart   = znorm + S_DIM;                   // 1412*128
    float* partial = hpart + T_CNT * H_CHUNKS * H_DIM;// 353
    float* dsum    = partial + T_CNT;                 // 4*128
    float* dsq     = dsum + DIST_B * H_DIM;           // 4*128

    pool_kernel<<<S_DIM + T_CNT * H_CHUNKS, 256, 0, stream>>>(
        all_h, all_z, Wz, bz, z_pool, znorm, hpart);
    nce_dist_kernel<<<T_CNT + DIST_B, 128, 0, stream>>>(
        hpart, Wh, bh, Wphi, bphi, z_pool, znorm, partial, dsum, dsq);
    final_kernel<<<1, 512, 0, stream>>>(partial, dsum, dsq, out);
}